// Round 1
// baseline (951.132 us; speedup 1.0000x reference)
//
#include <hip/hip_runtime.h>
#include <hip/hip_bf16.h>

#define IN_C 512
#define HID 64
#define OP_C 64
#define OUT_C 2

// ---------------- init ----------------
__global__ __launch_bounds__(256) void init_k(float* deg, int* cnt, int* cursor, int N) {
    int i = blockIdx.x * 256 + threadIdx.x;
    if (i < N) { deg[i] = 1.0f; cnt[i] = 0; cursor[i] = 0; }
}

// ---------------- degree + count pass ----------------
__global__ __launch_bounds__(256) void deg_k(const int* __restrict__ col,
                                             const float* __restrict__ attr,
                                             float* deg, int* cnt, int E) {
    int e = blockIdx.x * 256 + threadIdx.x;
    if (e >= E) return;
    float w = 1.0f / (attr[e] + 1.0f);
    int c = col[e];
    atomicAdd(&deg[c], w);
    atomicAdd(&cnt[c], 1);
}

__global__ __launch_bounds__(256) void dinv_k(const float* deg, float* dinv, int N) {
    int i = blockIdx.x * 256 + threadIdx.x;
    if (i < N) dinv[i] = rsqrtf(deg[i]);   // deg >= 1 always (self-loop)
}

// ---------------- hierarchical exclusive scan (count -> rowptr) ----------------
__global__ __launch_bounds__(256) void scan1_k(const int* __restrict__ cnt, int* rowptr,
                                               int* bsums, int N) {
    __shared__ int lds[256];
    int b = blockIdx.x, t = threadIdx.x;
    int base = b * 1024;
    int v[4]; int s = 0;
    #pragma unroll
    for (int j = 0; j < 4; ++j) {
        int idx = base + t * 4 + j;
        v[j] = (idx < N) ? cnt[idx] : 0;
        s += v[j];
    }
    lds[t] = s; __syncthreads();
    int x = s;
    for (int off = 1; off < 256; off <<= 1) {
        int y = (t >= off) ? lds[t - off] : 0;
        __syncthreads();
        x += y; lds[t] = x;
        __syncthreads();
    }
    int p = x - s;  // exclusive prefix within block
    #pragma unroll
    for (int j = 0; j < 4; ++j) {
        int idx = base + t * 4 + j;
        if (idx < N) rowptr[idx] = p;
        p += v[j];
    }
    if (t == 255) bsums[b] = x;  // block total (inclusive of all)
}

__global__ __launch_bounds__(256) void scan2_k(const int* bsums, int* boffs, int NB) {
    __shared__ int lds[256];
    int t = threadIdx.x;
    int v = (t < NB) ? bsums[t] : 0;
    lds[t] = v; __syncthreads();
    int x = v;
    for (int off = 1; off < 256; off <<= 1) {
        int y = (t >= off) ? lds[t - off] : 0;
        __syncthreads();
        x += y; lds[t] = x;
        __syncthreads();
    }
    if (t < NB) boffs[t] = x - v;
}

__global__ __launch_bounds__(256) void scan3_k(int* rowptr, const int* boffs, int N, int E) {
    int i = blockIdx.x * 256 + threadIdx.x;
    if (i < N) rowptr[i] += boffs[i >> 10];
    else if (i == N) rowptr[N] = E;
}

// ---------------- CSR fill ----------------
__global__ __launch_bounds__(256) void fill_k(const int* __restrict__ row,
                                              const int* __restrict__ col,
                                              const float* __restrict__ attr,
                                              const float* __restrict__ dinv,
                                              const int* __restrict__ rowptr,
                                              int* cursor, int* src, float* nrm, int E) {
    int e = blockIdx.x * 256 + threadIdx.x;
    if (e >= E) return;
    int r = row[e], c = col[e];
    float w = 1.0f / (attr[e] + 1.0f);
    float nv = dinv[r] * w * dinv[c];
    int pos = rowptr[c] + atomicAdd(&cursor[c], 1);
    src[pos] = r;
    nrm[pos] = nv;
}

// ---------------- fp32 GEMM: out[M,64] = A[M,K] @ W[K,64] ----------------
__global__ __launch_bounds__(256) void gemm_k(const float* __restrict__ A,
                                              const float* __restrict__ W,
                                              float* __restrict__ out, int M, int K) {
    __shared__ float xs[32][68];   // [k][m], padded
    __shared__ float ws[32][64];   // [k][n]
    int tid = threadIdx.x;
    int ty = tid >> 4, tx = tid & 15;
    long row0 = (long)blockIdx.x * 64;
    float accv[4][4] = {};
    for (int k0 = 0; k0 < K; k0 += 32) {
        #pragma unroll
        for (int r = 0; r < 2; ++r) {
            int i = tid + 256 * r;
            int rr = i >> 3, kc = i & 7;
            float4 v = make_float4(0.f, 0.f, 0.f, 0.f);
            long gr = row0 + rr;
            if (gr < M) v = *(const float4*)&A[gr * K + k0 + kc * 4];
            xs[kc * 4 + 0][rr] = v.x;
            xs[kc * 4 + 1][rr] = v.y;
            xs[kc * 4 + 2][rr] = v.z;
            xs[kc * 4 + 3][rr] = v.w;
        }
        #pragma unroll
        for (int r = 0; r < 2; ++r) {
            int i = tid + 256 * r;
            int kk = i >> 4, nc = i & 15;
            *(float4*)&ws[kk][nc * 4] = *(const float4*)&W[(long)(k0 + kk) * 64 + nc * 4];
        }
        __syncthreads();
        #pragma unroll
        for (int k = 0; k < 32; ++k) {
            float4 a = *(const float4*)&xs[k][ty * 4];
            float4 b = *(const float4*)&ws[k][tx * 4];
            float av[4] = {a.x, a.y, a.z, a.w};
            float bv[4] = {b.x, b.y, b.z, b.w};
            #pragma unroll
            for (int r = 0; r < 4; ++r)
                #pragma unroll
                for (int c = 0; c < 4; ++c)
                    accv[r][c] += av[r] * bv[c];
        }
        __syncthreads();
    }
    #pragma unroll
    for (int r = 0; r < 4; ++r) {
        long gr = row0 + ty * 4 + r;
        if (gr < M) {
            float4 o = make_float4(accv[r][0], accv[r][1], accv[r][2], accv[r][3]);
            *(float4*)&out[gr * 64 + tx * 4] = o;
        }
    }
}

// ---------------- aggregation: wave per node, lane = feature ----------------
__global__ __launch_bounds__(256) void agg_k(const float* __restrict__ h,
                                             float* __restrict__ g,
                                             const int* __restrict__ rowptr,
                                             const int* __restrict__ src,
                                             const float* __restrict__ nrm,
                                             const float* __restrict__ dinv,
                                             const float* __restrict__ bias, int N) {
    int wid = (blockIdx.x * 256 + threadIdx.x) >> 6;
    int lane = threadIdx.x & 63;
    if (wid >= N) return;
    float di = dinv[wid];
    float acc = di * di * h[(size_t)wid * 64 + lane];  // self loop (w=1)
    int s = rowptr[wid], e = rowptr[wid + 1];
    int i = s;
    for (; i + 3 < e; i += 4) {
        int s0 = src[i], s1 = src[i + 1], s2 = src[i + 2], s3 = src[i + 3];
        float n0 = nrm[i], n1 = nrm[i + 1], n2 = nrm[i + 2], n3 = nrm[i + 3];
        float h0 = h[(size_t)s0 * 64 + lane];
        float h1 = h[(size_t)s1 * 64 + lane];
        float h2 = h[(size_t)s2 * 64 + lane];
        float h3 = h[(size_t)s3 * 64 + lane];
        acc += n0 * h0 + n1 * h1 + n2 * h2 + n3 * h3;
    }
    for (; i < e; ++i) acc += nrm[i] * h[(size_t)src[i] * 64 + lane];
    acc += bias[lane];
    g[(size_t)wid * 64 + lane] = fmaxf(acc, 0.0f);
}

// ---------------- fold Wp@Wfc_top and bp@Wfc_top+bfc ----------------
__global__ __launch_bounds__(256) void prem_k(const float* __restrict__ Wp,
                                              const float* __restrict__ bp,
                                              const float* __restrict__ Wfc,
                                              const float* __restrict__ bfc,
                                              float* M, float* cvec) {
    int t = threadIdx.x;
    if (t < 128) {
        int k = t >> 1, j = t & 1;
        float s = 0.f;
        for (int f = 0; f < IN_C; ++f) s += Wp[k * IN_C + f] * Wfc[f * 2 + j];
        M[t] = s;  // M[k*2+j]
    } else if (t < 130) {
        int j = t - 128;
        float s = bfc[j];
        for (int f = 0; f < IN_C; ++f) s += bp[f] * Wfc[f * 2 + j];
        cvec[j] = s;
    }
}

// ---------------- fused final: out = g@M + op@Wfc_bot + cvec ----------------
__global__ __launch_bounds__(256) void final_k(const float* __restrict__ g,
                                               const float* __restrict__ op,
                                               const float* __restrict__ M,
                                               const float* __restrict__ Wfc,
                                               const float* __restrict__ cvec,
                                               float* __restrict__ out, int N) {
    int wid = (blockIdx.x * 256 + threadIdx.x) >> 6;
    int lane = threadIdx.x & 63;
    if (wid >= N) return;
    float a = g[(size_t)wid * 64 + lane];
    float o = op[(size_t)wid * 64 + lane];
    float p0 = a * M[lane * 2 + 0] + o * Wfc[(IN_C + lane) * 2 + 0];
    float p1 = a * M[lane * 2 + 1] + o * Wfc[(IN_C + lane) * 2 + 1];
    for (int off = 32; off > 0; off >>= 1) {
        p0 += __shfl_xor(p0, off);
        p1 += __shfl_xor(p1, off);
    }
    if (lane == 0) {
        out[(size_t)wid * 2 + 0] = p0 + cvec[0];
        out[(size_t)wid * 2 + 1] = p1 + cvec[1];
    }
}

extern "C" void kernel_launch(void* const* d_in, const int* in_sizes, int n_in,
                              void* d_out, int out_size, void* d_ws, size_t ws_size,
                              hipStream_t stream) {
    const float* x    = (const float*)d_in[0];
    const int*   ei   = (const int*)d_in[1];
    const float* attr = (const float*)d_in[2];
    const float* op   = (const float*)d_in[3];
    const float* W1   = (const float*)d_in[4];
    const float* b1   = (const float*)d_in[5];
    const float* W2   = (const float*)d_in[6];
    const float* b2   = (const float*)d_in[7];
    const float* Wp   = (const float*)d_in[8];
    const float* bp   = (const float*)d_in[9];
    const float* Wfc  = (const float*)d_in[10];
    const float* bfc  = (const float*)d_in[11];

    const int N = in_sizes[0] / IN_C;
    const int E = in_sizes[2];
    const int* row = ei;
    const int* col = ei + E;

    char* base = (char*)d_ws;
    size_t off = 0;
    auto alloc = [&](size_t bytes) -> char* {
        char* p = base + off;
        off = (off + bytes + 255) & ~(size_t)255;
        return p;
    };
    float* h      = (float*)alloc((size_t)N * HID * 4);
    float* g      = (float*)alloc((size_t)N * HID * 4);
    float* deg    = (float*)alloc((size_t)N * 4);
    float* dinv   = (float*)alloc((size_t)N * 4);
    int*   cnt    = (int*)alloc((size_t)N * 4);
    int*   rowptr = (int*)alloc((size_t)(N + 1) * 4);
    int*   cursor = (int*)alloc((size_t)N * 4);
    int*   srcb   = (int*)alloc((size_t)E * 4);
    float* nrmb   = (float*)alloc((size_t)E * 4);
    int*   bsums  = (int*)alloc(1024);
    int*   boffs  = (int*)alloc(1024);
    float* Mbuf   = (float*)alloc(512);
    float* cvec   = (float*)alloc(64);

    const int gN   = (N + 255) / 256;
    const int gE   = (E + 255) / 256;
    const int NB   = (N + 1023) / 1024;

    init_k<<<gN, 256, 0, stream>>>(deg, cnt, cursor, N);
    prem_k<<<1, 256, 0, stream>>>(Wp, bp, Wfc, bfc, Mbuf, cvec);
    deg_k<<<gE, 256, 0, stream>>>(col, attr, deg, cnt, E);
    dinv_k<<<gN, 256, 0, stream>>>(deg, dinv, N);
    scan1_k<<<NB, 256, 0, stream>>>(cnt, rowptr, bsums, N);
    scan2_k<<<1, 256, 0, stream>>>(bsums, boffs, NB);
    scan3_k<<<(N + 256) / 256, 256, 0, stream>>>(rowptr, boffs, N, E);
    fill_k<<<gE, 256, 0, stream>>>(row, col, attr, dinv, rowptr, cursor, srcb, nrmb, E);

    // conv1: h = x @ W1 ; g = relu(agg(h) + b1)
    gemm_k<<<(N + 63) / 64, 256, 0, stream>>>(x, W1, h, N, IN_C);
    agg_k<<<(N * 64 + 255) / 256, 256, 0, stream>>>(h, g, rowptr, srcb, nrmb, dinv, b1, N);
    // conv2: h = g @ W2 ; g = relu(agg(h) + b2)
    gemm_k<<<(N + 63) / 64, 256, 0, stream>>>(g, W2, h, N, HID);
    agg_k<<<(N * 64 + 255) / 256, 256, 0, stream>>>(h, g, rowptr, srcb, nrmb, dinv, b2, N);
    // fused final
    final_k<<<(N * 64 + 255) / 256, 256, 0, stream>>>(g, op, Mbuf, Wfc, cvec, (float*)d_out, N);
}

// Round 2
// 678.224 us; speedup vs baseline: 1.4024x; 1.4024x over previous
//
#include <hip/hip_runtime.h>
#include <hip/hip_bf16.h>

#define IN_C 512
#define HID 64
#define OP_C 64
#define OUT_C 2

// packed degree/count: low 48 bits = sum(w) in 2^32 fixed point, high 16 = count
#define CNT_SHIFT 48
#define W_SCALE 4294967296.0f  // 2^32

// ---------------- init ----------------
__global__ __launch_bounds__(256) void init_k(unsigned long long* packed, int N) {
    int i = blockIdx.x * 256 + threadIdx.x;
    if (i < N) packed[i] = (1ULL << 32);  // self-loop weight 1.0 (fixed point), count 0
}

// ---------------- degree + count + rank pass (single u64 atomic per edge) ----
__global__ __launch_bounds__(256) void deg_cnt_k(const int* __restrict__ col,
                                                 const float* __restrict__ attr,
                                                 unsigned long long* __restrict__ packed,
                                                 int* __restrict__ rank, int E) {
    int e = blockIdx.x * 256 + threadIdx.x;
    if (e >= E) return;
    float w = 1.0f / (attr[e] + 1.0f);
    unsigned long long wfix = (unsigned long long)(w * W_SCALE);
    unsigned long long old = atomicAdd(&packed[col[e]], wfix + (1ULL << CNT_SHIFT));
    rank[e] = (int)(old >> CNT_SHIFT);
}

__global__ __launch_bounds__(256) void dinv_k(const unsigned long long* __restrict__ packed,
                                              float* dinv, int N) {
    int i = blockIdx.x * 256 + threadIdx.x;
    if (i < N) {
        double deg = (double)(packed[i] & ((1ULL << CNT_SHIFT) - 1)) * (1.0 / (double)W_SCALE);
        dinv[i] = rsqrtf((float)deg);  // deg >= 1 always (self-loop)
    }
}

// ---------------- hierarchical exclusive scan (count -> rowptr) ----------------
__global__ __launch_bounds__(256) void scan1_k(const unsigned long long* __restrict__ packed,
                                               int* rowptr, int* bsums, int N) {
    __shared__ int lds[256];
    int b = blockIdx.x, t = threadIdx.x;
    int base = b * 1024;
    int v[4]; int s = 0;
    #pragma unroll
    for (int j = 0; j < 4; ++j) {
        int idx = base + t * 4 + j;
        v[j] = (idx < N) ? (int)(packed[idx] >> CNT_SHIFT) : 0;
        s += v[j];
    }
    lds[t] = s; __syncthreads();
    int x = s;
    for (int off = 1; off < 256; off <<= 1) {
        int y = (t >= off) ? lds[t - off] : 0;
        __syncthreads();
        x += y; lds[t] = x;
        __syncthreads();
    }
    int p = x - s;  // exclusive prefix within block
    #pragma unroll
    for (int j = 0; j < 4; ++j) {
        int idx = base + t * 4 + j;
        if (idx < N) rowptr[idx] = p;
        p += v[j];
    }
    if (t == 255) bsums[b] = x;
}

__global__ __launch_bounds__(256) void scan2_k(const int* bsums, int* boffs, int NB) {
    __shared__ int lds[256];
    int t = threadIdx.x;
    int v = (t < NB) ? bsums[t] : 0;
    lds[t] = v; __syncthreads();
    int x = v;
    for (int off = 1; off < 256; off <<= 1) {
        int y = (t >= off) ? lds[t - off] : 0;
        __syncthreads();
        x += y; lds[t] = x;
        __syncthreads();
    }
    if (t < NB) boffs[t] = x - v;
}

__global__ __launch_bounds__(256) void scan3_k(int* rowptr, const int* boffs, int N, int E) {
    int i = blockIdx.x * 256 + threadIdx.x;
    if (i < N) rowptr[i] += boffs[i >> 10];
    else if (i == N) rowptr[N] = E;
}

// ---------------- CSR fill (atomic-free, packed 8B store) ----------------
__global__ __launch_bounds__(256) void fill_k(const int* __restrict__ row,
                                              const int* __restrict__ col,
                                              const float* __restrict__ attr,
                                              const float* __restrict__ dinv,
                                              const int* __restrict__ rowptr,
                                              const int* __restrict__ rank,
                                              int2* __restrict__ edges, int E) {
    int e = blockIdx.x * 256 + threadIdx.x;
    if (e >= E) return;
    int r = row[e], c = col[e];
    float w = 1.0f / (attr[e] + 1.0f);
    float nv = dinv[r] * w * dinv[c];
    int pos = rowptr[c] + rank[e];
    edges[pos] = make_int2(r, __float_as_int(nv));
}

// ---------------- fp32 GEMM: out[M,64] = A[M,K] @ W[K,64] ----------------
__global__ __launch_bounds__(256) void gemm_k(const float* __restrict__ A,
                                              const float* __restrict__ W,
                                              float* __restrict__ out, int M, int K) {
    __shared__ float xs[32][68];   // [k][m], padded
    __shared__ float ws[32][64];   // [k][n]
    int tid = threadIdx.x;
    int ty = tid >> 4, tx = tid & 15;
    long row0 = (long)blockIdx.x * 64;
    float accv[4][4] = {};
    for (int k0 = 0; k0 < K; k0 += 32) {
        #pragma unroll
        for (int r = 0; r < 2; ++r) {
            int i = tid + 256 * r;
            int rr = i >> 3, kc = i & 7;
            float4 v = make_float4(0.f, 0.f, 0.f, 0.f);
            long gr = row0 + rr;
            if (gr < M) v = *(const float4*)&A[gr * K + k0 + kc * 4];
            xs[kc * 4 + 0][rr] = v.x;
            xs[kc * 4 + 1][rr] = v.y;
            xs[kc * 4 + 2][rr] = v.z;
            xs[kc * 4 + 3][rr] = v.w;
        }
        #pragma unroll
        for (int r = 0; r < 2; ++r) {
            int i = tid + 256 * r;
            int kk = i >> 4, nc = i & 15;
            *(float4*)&ws[kk][nc * 4] = *(const float4*)&W[(long)(k0 + kk) * 64 + nc * 4];
        }
        __syncthreads();
        #pragma unroll
        for (int k = 0; k < 32; ++k) {
            float4 a = *(const float4*)&xs[k][ty * 4];
            float4 b = *(const float4*)&ws[k][tx * 4];
            float av[4] = {a.x, a.y, a.z, a.w};
            float bv[4] = {b.x, b.y, b.z, b.w};
            #pragma unroll
            for (int r = 0; r < 4; ++r)
                #pragma unroll
                for (int c = 0; c < 4; ++c)
                    accv[r][c] += av[r] * bv[c];
        }
        __syncthreads();
    }
    #pragma unroll
    for (int r = 0; r < 4; ++r) {
        long gr = row0 + ty * 4 + r;
        if (gr < M) {
            float4 o = make_float4(accv[r][0], accv[r][1], accv[r][2], accv[r][3]);
            *(float4*)&out[gr * 64 + tx * 4] = o;
        }
    }
}

// ---------------- aggregation: wave per node, lane = feature ----------------
__global__ __launch_bounds__(256) void agg_k(const float* __restrict__ h,
                                             float* __restrict__ g,
                                             const int* __restrict__ rowptr,
                                             const int2* __restrict__ edges,
                                             const float* __restrict__ dinv,
                                             const float* __restrict__ bias, int N) {
    int wid = (blockIdx.x * 256 + threadIdx.x) >> 6;
    int lane = threadIdx.x & 63;
    if (wid >= N) return;
    float di = dinv[wid];
    float acc = di * di * h[(size_t)wid * 64 + lane];  // self loop (w=1)
    int s = rowptr[wid], e = rowptr[wid + 1];
    int i = s;
    for (; i + 3 < e; i += 4) {
        int2 p0 = edges[i], p1 = edges[i + 1], p2 = edges[i + 2], p3 = edges[i + 3];
        float h0 = h[(size_t)p0.x * 64 + lane];
        float h1 = h[(size_t)p1.x * 64 + lane];
        float h2 = h[(size_t)p2.x * 64 + lane];
        float h3 = h[(size_t)p3.x * 64 + lane];
        acc += __int_as_float(p0.y) * h0 + __int_as_float(p1.y) * h1
             + __int_as_float(p2.y) * h2 + __int_as_float(p3.y) * h3;
    }
    for (; i < e; ++i) {
        int2 p = edges[i];
        acc += __int_as_float(p.y) * h[(size_t)p.x * 64 + lane];
    }
    acc += bias[lane];
    g[(size_t)wid * 64 + lane] = fmaxf(acc, 0.0f);
}

// ---------------- fold Wp@Wfc_top and bp@Wfc_top+bfc ----------------
__global__ __launch_bounds__(256) void prem_k(const float* __restrict__ Wp,
                                              const float* __restrict__ bp,
                                              const float* __restrict__ Wfc,
                                              const float* __restrict__ bfc,
                                              float* M, float* cvec) {
    int t = threadIdx.x;
    if (t < 128) {
        int k = t >> 1, j = t & 1;
        float s = 0.f;
        for (int f = 0; f < IN_C; ++f) s += Wp[k * IN_C + f] * Wfc[f * 2 + j];
        M[t] = s;  // M[k*2+j]
    } else if (t < 130) {
        int j = t - 128;
        float s = bfc[j];
        for (int f = 0; f < IN_C; ++f) s += bp[f] * Wfc[f * 2 + j];
        cvec[j] = s;
    }
}

// ---------------- fused final: out = g@M + op@Wfc_bot + cvec ----------------
__global__ __launch_bounds__(256) void final_k(const float* __restrict__ g,
                                               const float* __restrict__ op,
                                               const float* __restrict__ M,
                                               const float* __restrict__ Wfc,
                                               const float* __restrict__ cvec,
                                               float* __restrict__ out, int N) {
    int wid = (blockIdx.x * 256 + threadIdx.x) >> 6;
    int lane = threadIdx.x & 63;
    if (wid >= N) return;
    float a = g[(size_t)wid * 64 + lane];
    float o = op[(size_t)wid * 64 + lane];
    float p0 = a * M[lane * 2 + 0] + o * Wfc[(IN_C + lane) * 2 + 0];
    float p1 = a * M[lane * 2 + 1] + o * Wfc[(IN_C + lane) * 2 + 1];
    for (int off = 32; off > 0; off >>= 1) {
        p0 += __shfl_xor(p0, off);
        p1 += __shfl_xor(p1, off);
    }
    if (lane == 0) {
        out[(size_t)wid * 2 + 0] = p0 + cvec[0];
        out[(size_t)wid * 2 + 1] = p1 + cvec[1];
    }
}

extern "C" void kernel_launch(void* const* d_in, const int* in_sizes, int n_in,
                              void* d_out, int out_size, void* d_ws, size_t ws_size,
                              hipStream_t stream) {
    const float* x    = (const float*)d_in[0];
    const int*   ei   = (const int*)d_in[1];
    const float* attr = (const float*)d_in[2];
    const float* op   = (const float*)d_in[3];
    const float* W1   = (const float*)d_in[4];
    const float* b1   = (const float*)d_in[5];
    const float* W2   = (const float*)d_in[6];
    const float* b2   = (const float*)d_in[7];
    const float* Wp   = (const float*)d_in[8];
    const float* bp   = (const float*)d_in[9];
    const float* Wfc  = (const float*)d_in[10];
    const float* bfc  = (const float*)d_in[11];

    const int N = in_sizes[0] / IN_C;
    const int E = in_sizes[2];
    const int* row = ei;
    const int* col = ei + E;

    char* base = (char*)d_ws;
    size_t off = 0;
    auto alloc = [&](size_t bytes) -> char* {
        char* p = base + off;
        off = (off + bytes + 255) & ~(size_t)255;
        return p;
    };
    // h overlays rank: rank[E] (12.8MB) is dead before gemm1 writes h (25.6MB)
    float* h      = (float*)alloc((size_t)N * HID * 4);
    int*   rank   = (int*)h;
    float* g      = (float*)alloc((size_t)N * HID * 4);
    unsigned long long* packed = (unsigned long long*)alloc((size_t)N * 8);
    float* dinv   = (float*)alloc((size_t)N * 4);
    int*   rowptr = (int*)alloc((size_t)(N + 1) * 4);
    int2*  edges  = (int2*)alloc((size_t)E * 8);
    int*   bsums  = (int*)alloc(1024);
    int*   boffs  = (int*)alloc(1024);
    float* Mbuf   = (float*)alloc(512);
    float* cvec   = (float*)alloc(64);

    const int gN   = (N + 255) / 256;
    const int gE   = (E + 255) / 256;
    const int NB   = (N + 1023) / 1024;

    init_k<<<gN, 256, 0, stream>>>(packed, N);
    prem_k<<<1, 256, 0, stream>>>(Wp, bp, Wfc, bfc, Mbuf, cvec);
    deg_cnt_k<<<gE, 256, 0, stream>>>(col, attr, packed, rank, E);
    dinv_k<<<gN, 256, 0, stream>>>(packed, dinv, N);
    scan1_k<<<NB, 256, 0, stream>>>(packed, rowptr, bsums, N);
    scan2_k<<<1, 256, 0, stream>>>(bsums, boffs, NB);
    scan3_k<<<(N + 256) / 256, 256, 0, stream>>>(rowptr, boffs, N, E);
    fill_k<<<gE, 256, 0, stream>>>(row, col, attr, dinv, rowptr, rank, edges, E);

    // conv1: h = x @ W1 ; g = relu(agg(h) + b1)   (h overwrites rank — rank is dead now)
    gemm_k<<<(N + 63) / 64, 256, 0, stream>>>(x, W1, h, N, IN_C);
    agg_k<<<(N * 64 + 255) / 256, 256, 0, stream>>>(h, g, rowptr, edges, dinv, b1, N);
    // conv2: h = g @ W2 ; g = relu(agg(h) + b2)
    gemm_k<<<(N + 63) / 64, 256, 0, stream>>>(g, W2, h, N, HID);
    agg_k<<<(N * 64 + 255) / 256, 256, 0, stream>>>(h, g, rowptr, edges, dinv, b2, N);
    // fused final
    final_k<<<(N * 64 + 255) / 256, 256, 0, stream>>>(g, op, Mbuf, Wfc, cvec, (float*)d_out, N);
}

// Round 3
// 626.386 us; speedup vs baseline: 1.5184x; 1.0828x over previous
//
#include <hip/hip_runtime.h>
#include <hip/hip_bf16.h>

#define IN_C 512
#define HID 64
#define OP_C 64
#define OUT_C 2

#define NPB 128          // nodes per coarse bucket (power of 2)
#define NPB_SHIFT 7
#define MAXB 1024        // max buckets (N <= 131072)
#define EPT 32           // edges per thread in binning
#define BINB 256         // binning block size
#define EPB (EPT*BINB)   // 8192 edges per binning block
#define WFIX 16777216.0f // 2^24 fixed-point scale for weight sums

// ---------------- zero bucket counters ----------------
__global__ __launch_bounds__(256) void zero_k(int* gcnt, int B) {
    int i = blockIdx.x * 256 + threadIdx.x;
    if (i < B) gcnt[i] = 0;
}

// ---------------- P1a: per-block histogram + space reservation ----------------
__global__ __launch_bounds__(BINB) void p1a_k(const int* __restrict__ col,
                                              int* __restrict__ gcnt,
                                              int* __restrict__ blk_off,
                                              int E, int B) {
    __shared__ int hist[MAXB];
    int tid = threadIdx.x;
    long e0 = (long)blockIdx.x * EPB;
    for (int i = tid; i < B; i += BINB) hist[i] = 0;
    __syncthreads();
    #pragma unroll
    for (int j = 0; j < EPT; ++j) {
        long e = e0 + j * BINB + tid;
        if (e < E) atomicAdd(&hist[col[e] >> NPB_SHIFT], 1);
    }
    __syncthreads();
    for (int b = tid; b < B; b += BINB) {
        int h = hist[b];
        if (h > 0) blk_off[(long)blockIdx.x * MAXB + b] = atomicAdd(&gcnt[b], h);
    }
}

// ---------------- single-block exclusive scan: gcnt -> bptr, bptr[B]=E -------
__global__ __launch_bounds__(256) void scanB_k(const int* __restrict__ gcnt,
                                               int* __restrict__ bptr, int B, int E) {
    __shared__ int lds[256];
    int t = threadIdx.x;
    int v[4]; int s = 0;
    #pragma unroll
    for (int j = 0; j < 4; ++j) { int i = t * 4 + j; v[j] = (i < B) ? gcnt[i] : 0; s += v[j]; }
    lds[t] = s; __syncthreads();
    int x = s;
    for (int off = 1; off < 256; off <<= 1) {
        int y = (t >= off) ? lds[t - off] : 0;
        __syncthreads();
        x += y; lds[t] = x;
        __syncthreads();
    }
    int p = x - s;
    #pragma unroll
    for (int j = 0; j < 4; ++j) { int i = t * 4 + j; if (i < B) bptr[i] = p; p += v[j]; }
    if (t == 255) bptr[B] = E;
}

// ---------------- P1b: scatter edges into coarse buckets (no global atomics) -
__global__ __launch_bounds__(BINB) void p1b_k(const int* __restrict__ row,
                                              const int* __restrict__ col,
                                              const float* __restrict__ attr,
                                              const int* __restrict__ blk_off,
                                              const int* __restrict__ bptr,
                                              int2* __restrict__ bsw,
                                              int* __restrict__ bcol,
                                              int E, int B) {
    __shared__ int cur[MAXB];
    int tid = threadIdx.x;
    long e0 = (long)blockIdx.x * EPB;
    for (int i = tid; i < B; i += BINB) cur[i] = 0;
    __syncthreads();
    #pragma unroll
    for (int j = 0; j < EPT; ++j) {
        long e = e0 + j * BINB + tid;
        if (e < E) {
            int c = col[e];
            int b = c >> NPB_SHIFT;
            int r = atomicAdd(&cur[b], 1);
            int pos = bptr[b] + blk_off[(long)blockIdx.x * MAXB + b] + r;
            float w = 1.0f / (attr[e] + 1.0f);
            bsw[pos] = make_int2(row[e], __float_as_int(w));
            bcol[pos] = c;
        }
    }
}

// ---------------- P2: per-bucket exact CSR build (block owns bucket) ---------
__global__ __launch_bounds__(256) void p2_k(const int2* __restrict__ bsw,
                                            const int* __restrict__ bcol,
                                            const int* __restrict__ bptr,
                                            int2* __restrict__ edges,
                                            int* __restrict__ rowptr,
                                            float* __restrict__ dinv,
                                            int N, int E) {
    __shared__ int cnt[NPB];
    __shared__ unsigned int fxw[NPB];
    __shared__ int excl[NPB];
    __shared__ int cur[NPB];
    __shared__ float dvl[NPB];
    int tid = threadIdx.x;
    int b = blockIdx.x;
    int e0 = bptr[b], e1 = bptr[b + 1];
    int c0 = b << NPB_SHIFT;
    if (tid < NPB) { cnt[tid] = 0; fxw[tid] = 0; cur[tid] = 0; }
    if (b == 0 && tid == 0) rowptr[N] = E;
    __syncthreads();
    for (int i = e0 + tid; i < e1; i += 256) {
        int lc = bcol[i] & (NPB - 1);
        float w = __int_as_float(bsw[i].y);
        atomicAdd(&cnt[lc], 1);
        atomicAdd(&fxw[lc], (unsigned int)(w * WFIX));
    }
    __syncthreads();
    if (tid < NPB) excl[tid] = cnt[tid];
    __syncthreads();
    for (int off = 1; off < NPB; off <<= 1) {
        int v = 0;
        if (tid < NPB && tid >= off) v = excl[tid - off];
        __syncthreads();
        if (tid < NPB) excl[tid] += v;
        __syncthreads();
    }
    if (tid < NPB) {
        int ex = excl[tid] - cnt[tid];   // inclusive -> exclusive
        excl[tid] = ex;
        int c = c0 + tid;
        if (c < N) {
            rowptr[c] = e0 + ex;
            float deg = 1.0f + (float)((double)fxw[tid] * (1.0 / 16777216.0));
            float dv = rsqrtf(deg);
            dinv[c] = dv;
            dvl[tid] = dv;
        }
    }
    __syncthreads();
    for (int i = e0 + tid; i < e1; i += 256) {
        int lc = bcol[i] & (NPB - 1);
        int r = atomicAdd(&cur[lc], 1);
        int2 sw = bsw[i];
        float nrm_p = __int_as_float(sw.y) * dvl[lc];  // w * dinv[col]; dinv[src] folded in agg
        edges[e0 + excl[lc] + r] = make_int2(sw.x, __float_as_int(nrm_p));
    }
}

// ---------------- fp32 GEMM: out[M,64] = A[M,K] @ W[K,64] ----------------
__global__ __launch_bounds__(256) void gemm_k(const float* __restrict__ A,
                                              const float* __restrict__ W,
                                              float* __restrict__ out, int M, int K) {
    __shared__ float xs[32][68];
    __shared__ float ws[32][64];
    int tid = threadIdx.x;
    int ty = tid >> 4, tx = tid & 15;
    long row0 = (long)blockIdx.x * 64;
    float accv[4][4] = {};
    for (int k0 = 0; k0 < K; k0 += 32) {
        #pragma unroll
        for (int r = 0; r < 2; ++r) {
            int i = tid + 256 * r;
            int rr = i >> 3, kc = i & 7;
            float4 v = make_float4(0.f, 0.f, 0.f, 0.f);
            long gr = row0 + rr;
            if (gr < M) v = *(const float4*)&A[gr * K + k0 + kc * 4];
            xs[kc * 4 + 0][rr] = v.x;
            xs[kc * 4 + 1][rr] = v.y;
            xs[kc * 4 + 2][rr] = v.z;
            xs[kc * 4 + 3][rr] = v.w;
        }
        #pragma unroll
        for (int r = 0; r < 2; ++r) {
            int i = tid + 256 * r;
            int kk = i >> 4, nc = i & 15;
            *(float4*)&ws[kk][nc * 4] = *(const float4*)&W[(long)(k0 + kk) * 64 + nc * 4];
        }
        __syncthreads();
        #pragma unroll
        for (int k = 0; k < 32; ++k) {
            float4 a = *(const float4*)&xs[k][ty * 4];
            float4 b = *(const float4*)&ws[k][tx * 4];
            float av[4] = {a.x, a.y, a.z, a.w};
            float bv[4] = {b.x, b.y, b.z, b.w};
            #pragma unroll
            for (int r = 0; r < 4; ++r)
                #pragma unroll
                for (int c = 0; c < 4; ++c)
                    accv[r][c] += av[r] * bv[c];
        }
        __syncthreads();
    }
    #pragma unroll
    for (int r = 0; r < 4; ++r) {
        long gr = row0 + ty * 4 + r;
        if (gr < M) {
            float4 o = make_float4(accv[r][0], accv[r][1], accv[r][2], accv[r][3]);
            *(float4*)&out[gr * 64 + tx * 4] = o;
        }
    }
}

// ---------------- aggregation: wave per node, lane = feature ----------------
__global__ __launch_bounds__(256) void agg_k(const float* __restrict__ h,
                                             float* __restrict__ g,
                                             const int* __restrict__ rowptr,
                                             const int2* __restrict__ edges,
                                             const float* __restrict__ dinv,
                                             const float* __restrict__ bias, int N) {
    int wid = (blockIdx.x * 256 + threadIdx.x) >> 6;
    int lane = threadIdx.x & 63;
    if (wid >= N) return;
    float di = dinv[wid];
    float acc = di * di * h[(size_t)wid * 64 + lane];  // self loop (w=1)
    int s = rowptr[wid], e = rowptr[wid + 1];
    int i = s;
    for (; i + 3 < e; i += 4) {
        int2 p0 = edges[i], p1 = edges[i + 1], p2 = edges[i + 2], p3 = edges[i + 3];
        float n0 = __int_as_float(p0.y) * dinv[p0.x];
        float n1 = __int_as_float(p1.y) * dinv[p1.x];
        float n2 = __int_as_float(p2.y) * dinv[p2.x];
        float n3 = __int_as_float(p3.y) * dinv[p3.x];
        float h0 = h[(size_t)p0.x * 64 + lane];
        float h1 = h[(size_t)p1.x * 64 + lane];
        float h2 = h[(size_t)p2.x * 64 + lane];
        float h3 = h[(size_t)p3.x * 64 + lane];
        acc += n0 * h0 + n1 * h1 + n2 * h2 + n3 * h3;
    }
    for (; i < e; ++i) {
        int2 p = edges[i];
        acc += __int_as_float(p.y) * dinv[p.x] * h[(size_t)p.x * 64 + lane];
    }
    acc += bias[lane];
    g[(size_t)wid * 64 + lane] = fmaxf(acc, 0.0f);
}

// ---------------- fold Wp@Wfc_top and bp@Wfc_top+bfc ----------------
__global__ __launch_bounds__(256) void prem_k(const float* __restrict__ Wp,
                                              const float* __restrict__ bp,
                                              const float* __restrict__ Wfc,
                                              const float* __restrict__ bfc,
                                              float* M, float* cvec) {
    int t = threadIdx.x;
    if (t < 128) {
        int k = t >> 1, j = t & 1;
        float s = 0.f;
        for (int f = 0; f < IN_C; ++f) s += Wp[k * IN_C + f] * Wfc[f * 2 + j];
        M[t] = s;
    } else if (t < 130) {
        int j = t - 128;
        float s = bfc[j];
        for (int f = 0; f < IN_C; ++f) s += bp[f] * Wfc[f * 2 + j];
        cvec[j] = s;
    }
}

// ---------------- fused final: out = g@M + op@Wfc_bot + cvec ----------------
__global__ __launch_bounds__(256) void final_k(const float* __restrict__ g,
                                               const float* __restrict__ op,
                                               const float* __restrict__ M,
                                               const float* __restrict__ Wfc,
                                               const float* __restrict__ cvec,
                                               float* __restrict__ out, int N) {
    int wid = (blockIdx.x * 256 + threadIdx.x) >> 6;
    int lane = threadIdx.x & 63;
    if (wid >= N) return;
    float a = g[(size_t)wid * 64 + lane];
    float o = op[(size_t)wid * 64 + lane];
    float p0 = a * M[lane * 2 + 0] + o * Wfc[(IN_C + lane) * 2 + 0];
    float p1 = a * M[lane * 2 + 1] + o * Wfc[(IN_C + lane) * 2 + 1];
    for (int off = 32; off > 0; off >>= 1) {
        p0 += __shfl_xor(p0, off);
        p1 += __shfl_xor(p1, off);
    }
    if (lane == 0) {
        out[(size_t)wid * 2 + 0] = p0 + cvec[0];
        out[(size_t)wid * 2 + 1] = p1 + cvec[1];
    }
}

extern "C" void kernel_launch(void* const* d_in, const int* in_sizes, int n_in,
                              void* d_out, int out_size, void* d_ws, size_t ws_size,
                              hipStream_t stream) {
    const float* x    = (const float*)d_in[0];
    const int*   ei   = (const int*)d_in[1];
    const float* attr = (const float*)d_in[2];
    const float* op   = (const float*)d_in[3];
    const float* W1   = (const float*)d_in[4];
    const float* b1   = (const float*)d_in[5];
    const float* W2   = (const float*)d_in[6];
    const float* b2   = (const float*)d_in[7];
    const float* Wp   = (const float*)d_in[8];
    const float* bp   = (const float*)d_in[9];
    const float* Wfc  = (const float*)d_in[10];
    const float* bfc  = (const float*)d_in[11];

    const int N = in_sizes[0] / IN_C;
    const int E = in_sizes[2];
    const int* row = ei;
    const int* col = ei + E;

    const int B     = (N + NPB - 1) >> NPB_SHIFT;     // coarse buckets (<= MAXB)
    const int nblk1 = (E + EPB - 1) / EPB;            // binning blocks

    char* base = (char*)d_ws;
    size_t off = 0;
    auto alloc = [&](size_t bytes) -> char* {
        char* p = base + off;
        off = (off + bytes + 255) & ~(size_t)255;
        return p;
    };
    int2*  edges  = (int2*)alloc((size_t)E * 8);          // persistent CSR
    // region A: binned_sw (E*8) -> later h (N*64*4)
    char*  regA   = alloc((size_t)E * 8 > (size_t)N * HID * 4 ? (size_t)E * 8 : (size_t)N * HID * 4);
    int2*  bsw    = (int2*)regA;
    float* h      = (float*)regA;
    // region B: binned_col (E*4) + blk_off (nblk1*MAXB*4)  -> later g (N*64*4)
    size_t bcol_b = (size_t)E * 4;
    size_t regB_b = bcol_b + ((size_t)nblk1 * MAXB * 4) + 256;
    size_t g_b    = (size_t)N * HID * 4;
    char*  regB   = alloc(regB_b > g_b ? regB_b : g_b);
    int*   bcol   = (int*)regB;
    int*   blkoff = (int*)(regB + ((bcol_b + 255) & ~(size_t)255));
    float* g      = (float*)regB;
    float* dinv   = (float*)alloc((size_t)N * 4);
    int*   rowptr = (int*)alloc((size_t)(N + 1) * 4);
    int*   gcnt   = (int*)alloc((size_t)MAXB * 4);
    int*   bptr   = (int*)alloc((size_t)(MAXB + 1) * 4);
    float* Mbuf   = (float*)alloc(512);
    float* cvec   = (float*)alloc(64);

    zero_k<<<(B + 255) / 256, 256, 0, stream>>>(gcnt, B);
    prem_k<<<1, 256, 0, stream>>>(Wp, bp, Wfc, bfc, Mbuf, cvec);
    p1a_k<<<nblk1, BINB, 0, stream>>>(col, gcnt, blkoff, E, B);
    scanB_k<<<1, 256, 0, stream>>>(gcnt, bptr, B, E);
    p1b_k<<<nblk1, BINB, 0, stream>>>(row, col, attr, blkoff, bptr, bsw, bcol, E, B);
    p2_k<<<B, 256, 0, stream>>>(bsw, bcol, bptr, edges, rowptr, dinv, N, E);

    // conv1: h = x @ W1 ; g = relu(agg(h) + b1)   (h overlays bsw — dead after p2)
    gemm_k<<<(N + 63) / 64, 256, 0, stream>>>(x, W1, h, N, IN_C);
    agg_k<<<(N * 64 + 255) / 256, 256, 0, stream>>>(h, g, rowptr, edges, dinv, b1, N);
    // conv2: h = g @ W2 ; g = relu(agg(h) + b2)
    gemm_k<<<(N + 63) / 64, 256, 0, stream>>>(g, W2, h, N, HID);
    agg_k<<<(N * 64 + 255) / 256, 256, 0, stream>>>(h, g, rowptr, edges, dinv, b2, N);
    // fused final
    final_k<<<(N * 64 + 255) / 256, 256, 0, stream>>>(g, op, Mbuf, Wfc, cvec, (float*)d_out, N);
}

// Round 4
// 499.128 us; speedup vs baseline: 1.9056x; 1.2550x over previous
//
#include <hip/hip_runtime.h>
#include <hip/hip_bf16.h>

#define IN_C 512
#define HID 64
#define OP_C 64
#define OUT_C 2

#define NPB 128          // nodes per coarse bucket
#define NPB_SHIFT 7
#define MAXB 1024        // max buckets (N <= 131072)
#define BINB 1024        // binning block size (big blocks -> occupancy w/o more atomics)
#define EPT 8            // edges per thread in binning
#define EPB (BINB*EPT)   // 8192 edges per binning block
#define WFIX 16777216.0f // 2^24 fixed-point scale for weight sums

static __device__ __forceinline__ unsigned short f2bf(float f) {
    unsigned int u = __float_as_uint(f);
    u = (u + 0x7FFFu + ((u >> 16) & 1u)) >> 16;   // RNE
    return (unsigned short)u;
}
static __device__ __forceinline__ float bf2f(unsigned short s) {
    return __uint_as_float(((unsigned int)s) << 16);
}

// ---------------- zero bucket counters ----------------
__global__ __launch_bounds__(256) void zero_k(int* gcnt, int B) {
    int i = blockIdx.x * 256 + threadIdx.x;
    if (i < B) gcnt[i] = 0;
}

// ---------------- P1a: per-block histogram + space reservation ----------------
__global__ __launch_bounds__(BINB) void p1a_k(const int* __restrict__ col,
                                              int* __restrict__ gcnt,
                                              int* __restrict__ blk_off,
                                              int E, int B) {
    __shared__ int hist[MAXB];
    int tid = threadIdx.x;
    long e0 = (long)blockIdx.x * EPB;
    for (int i = tid; i < B; i += BINB) hist[i] = 0;
    __syncthreads();
    #pragma unroll
    for (int j = 0; j < EPT; ++j) {
        long e = e0 + j * BINB + tid;
        if (e < E) atomicAdd(&hist[col[e] >> NPB_SHIFT], 1);
    }
    __syncthreads();
    for (int b = tid; b < B; b += BINB) {
        int h = hist[b];
        if (h > 0) blk_off[(long)blockIdx.x * MAXB + b] = atomicAdd(&gcnt[b], h);
    }
}

// ---------------- single-block exclusive scan: gcnt -> bptr, bptr[B]=E -------
__global__ __launch_bounds__(256) void scanB_k(const int* __restrict__ gcnt,
                                               int* __restrict__ bptr, int B, int E) {
    __shared__ int lds[256];
    int t = threadIdx.x;
    int v[4]; int s = 0;
    #pragma unroll
    for (int j = 0; j < 4; ++j) { int i = t * 4 + j; v[j] = (i < B) ? gcnt[i] : 0; s += v[j]; }
    lds[t] = s; __syncthreads();
    int x = s;
    for (int off = 1; off < 256; off <<= 1) {
        int y = (t >= off) ? lds[t - off] : 0;
        __syncthreads();
        x += y; lds[t] = x;
        __syncthreads();
    }
    int p = x - s;
    #pragma unroll
    for (int j = 0; j < 4; ++j) { int i = t * 4 + j; if (i < B) bptr[i] = p; p += v[j]; }
    if (t == 255) bptr[B] = E;
}

// ---------------- P1b: scatter edges into coarse buckets (no global atomics) -
__global__ __launch_bounds__(BINB) void p1b_k(const int* __restrict__ row,
                                              const int* __restrict__ col,
                                              const float* __restrict__ attr,
                                              const int* __restrict__ blk_off,
                                              const int* __restrict__ bptr,
                                              int2* __restrict__ bsw,
                                              int* __restrict__ bcol,
                                              int E, int B) {
    __shared__ int cur[MAXB];
    int tid = threadIdx.x;
    long e0 = (long)blockIdx.x * EPB;
    for (int i = tid; i < B; i += BINB) cur[i] = 0;
    __syncthreads();
    #pragma unroll
    for (int j = 0; j < EPT; ++j) {
        long e = e0 + j * BINB + tid;
        if (e < E) {
            int c = col[e];
            int b = c >> NPB_SHIFT;
            int r = atomicAdd(&cur[b], 1);
            int pos = bptr[b] + blk_off[(long)blockIdx.x * MAXB + b] + r;
            float w = 1.0f / (attr[e] + 1.0f);
            bsw[pos] = make_int2(row[e], __float_as_int(w));
            bcol[pos] = c;
        }
    }
}

// ---------------- P2: per-bucket exact CSR build (block owns bucket) ---------
__global__ __launch_bounds__(256) void p2_k(const int2* __restrict__ bsw,
                                            const int* __restrict__ bcol,
                                            const int* __restrict__ bptr,
                                            int2* __restrict__ edges,
                                            int* __restrict__ rowptr,
                                            float* __restrict__ dinv,
                                            int N, int E) {
    __shared__ int cnt[NPB];
    __shared__ unsigned int fxw[NPB];
    __shared__ int excl[NPB];
    __shared__ int cur[NPB];
    __shared__ float dvl[NPB];
    int tid = threadIdx.x;
    int b = blockIdx.x;
    int e0 = bptr[b], e1 = bptr[b + 1];
    int c0 = b << NPB_SHIFT;
    if (tid < NPB) { cnt[tid] = 0; fxw[tid] = 0; cur[tid] = 0; }
    if (b == 0 && tid == 0) rowptr[N] = E;
    __syncthreads();
    for (int i = e0 + tid; i < e1; i += 256) {
        int lc = bcol[i] & (NPB - 1);
        float w = __int_as_float(bsw[i].y);
        atomicAdd(&cnt[lc], 1);
        atomicAdd(&fxw[lc], (unsigned int)(w * WFIX));
    }
    __syncthreads();
    if (tid < NPB) excl[tid] = cnt[tid];
    __syncthreads();
    for (int off = 1; off < NPB; off <<= 1) {
        int v = 0;
        if (tid < NPB && tid >= off) v = excl[tid - off];
        __syncthreads();
        if (tid < NPB) excl[tid] += v;
        __syncthreads();
    }
    if (tid < NPB) {
        int ex = excl[tid] - cnt[tid];
        excl[tid] = ex;
        int c = c0 + tid;
        if (c < N) {
            rowptr[c] = e0 + ex;
            float deg = 1.0f + (float)((double)fxw[tid] * (1.0 / 16777216.0));
            float dv = rsqrtf(deg);
            dinv[c] = dv;
            dvl[tid] = dv;
        }
    }
    __syncthreads();
    for (int i = e0 + tid; i < e1; i += 256) {
        int lc = bcol[i] & (NPB - 1);
        int r = atomicAdd(&cur[lc], 1);
        int2 sw = bsw[i];
        float nrm_p = __int_as_float(sw.y) * dvl[lc];  // w*dinv[col]; dinv[src] folded in agg
        edges[e0 + excl[lc] + r] = make_int2(sw.x, __float_as_int(nrm_p));
    }
}

// ---------------- fp32 GEMM -> bf16 out: out[M,64] = A[M,K] @ W[K,64] --------
__global__ __launch_bounds__(256) void gemm_k(const float* __restrict__ A,
                                              const float* __restrict__ W,
                                              unsigned short* __restrict__ out,
                                              int M, int K) {
    __shared__ float xs[32][68];
    __shared__ float ws[32][64];
    int tid = threadIdx.x;
    int ty = tid >> 4, tx = tid & 15;
    long row0 = (long)blockIdx.x * 64;
    float accv[4][4] = {};
    for (int k0 = 0; k0 < K; k0 += 32) {
        #pragma unroll
        for (int r = 0; r < 2; ++r) {
            int i = tid + 256 * r;
            int rr = i >> 3, kc = i & 7;
            float4 v = make_float4(0.f, 0.f, 0.f, 0.f);
            long gr = row0 + rr;
            if (gr < M) v = *(const float4*)&A[gr * K + k0 + kc * 4];
            xs[kc * 4 + 0][rr] = v.x;
            xs[kc * 4 + 1][rr] = v.y;
            xs[kc * 4 + 2][rr] = v.z;
            xs[kc * 4 + 3][rr] = v.w;
        }
        #pragma unroll
        for (int r = 0; r < 2; ++r) {
            int i = tid + 256 * r;
            int kk = i >> 4, nc = i & 15;
            *(float4*)&ws[kk][nc * 4] = *(const float4*)&W[(long)(k0 + kk) * 64 + nc * 4];
        }
        __syncthreads();
        #pragma unroll
        for (int k = 0; k < 32; ++k) {
            float4 a = *(const float4*)&xs[k][ty * 4];
            float4 b = *(const float4*)&ws[k][tx * 4];
            float av[4] = {a.x, a.y, a.z, a.w};
            float bv[4] = {b.x, b.y, b.z, b.w};
            #pragma unroll
            for (int r = 0; r < 4; ++r)
                #pragma unroll
                for (int c = 0; c < 4; ++c)
                    accv[r][c] += av[r] * bv[c];
        }
        __syncthreads();
    }
    #pragma unroll
    for (int r = 0; r < 4; ++r) {
        long gr = row0 + ty * 4 + r;
        if (gr < M) {
            ushort4 o;
            o.x = f2bf(accv[r][0]); o.y = f2bf(accv[r][1]);
            o.z = f2bf(accv[r][2]); o.w = f2bf(accv[r][3]);
            *(ushort4*)&out[gr * 64 + tx * 4] = o;
        }
    }
}

// ---------------- agg core: 2 nodes per wave, bf16 gather --------------------
// half-wave (32 lanes) owns one node; lane holds features {2l, 2l+1}
__device__ __forceinline__ void agg_core(const unsigned short* __restrict__ h2,
                                         const int* __restrict__ rowptr,
                                         const int2* __restrict__ edges,
                                         const float* __restrict__ dinv,
                                         const float* __restrict__ bias,
                                         int node, int l,
                                         float& acc0, float& acc1) {
    float di = dinv[node];
    ushort2 hv = *(const ushort2*)(h2 + (size_t)node * 64 + 2 * l);
    acc0 = di * di * bf2f(hv.x);
    acc1 = di * di * bf2f(hv.y);
    int s = rowptr[node], e = rowptr[node + 1];
    int i = s;
    for (; i + 3 < e; i += 4) {
        int2 p0 = edges[i], p1 = edges[i + 1], p2 = edges[i + 2], p3 = edges[i + 3];
        float n0 = __int_as_float(p0.y) * dinv[p0.x];
        float n1 = __int_as_float(p1.y) * dinv[p1.x];
        float n2 = __int_as_float(p2.y) * dinv[p2.x];
        float n3 = __int_as_float(p3.y) * dinv[p3.x];
        ushort2 q0 = *(const ushort2*)(h2 + (size_t)p0.x * 64 + 2 * l);
        ushort2 q1 = *(const ushort2*)(h2 + (size_t)p1.x * 64 + 2 * l);
        ushort2 q2 = *(const ushort2*)(h2 + (size_t)p2.x * 64 + 2 * l);
        ushort2 q3 = *(const ushort2*)(h2 + (size_t)p3.x * 64 + 2 * l);
        acc0 += n0 * bf2f(q0.x) + n1 * bf2f(q1.x) + n2 * bf2f(q2.x) + n3 * bf2f(q3.x);
        acc1 += n0 * bf2f(q0.y) + n1 * bf2f(q1.y) + n2 * bf2f(q2.y) + n3 * bf2f(q3.y);
    }
    for (; i < e; ++i) {
        int2 p = edges[i];
        float n = __int_as_float(p.y) * dinv[p.x];
        ushort2 q = *(const ushort2*)(h2 + (size_t)p.x * 64 + 2 * l);
        acc0 += n * bf2f(q.x);
        acc1 += n * bf2f(q.y);
    }
    float2 b = *(const float2*)(bias + 2 * l);
    acc0 = fmaxf(acc0 + b.x, 0.0f);
    acc1 = fmaxf(acc1 + b.y, 0.0f);
}

// layer 1: write g fp32 (input to gemm2)
__global__ __launch_bounds__(256) void agg1_k(const unsigned short* __restrict__ h2,
                                              float* __restrict__ g,
                                              const int* __restrict__ rowptr,
                                              const int2* __restrict__ edges,
                                              const float* __restrict__ dinv,
                                              const float* __restrict__ bias, int N) {
    int wid = (blockIdx.x * 256 + threadIdx.x) >> 6;
    int lane = threadIdx.x & 63;
    int node = wid * 2 + (lane >> 5);
    int l = lane & 31;
    if (node >= N) return;
    float acc0, acc1;
    agg_core(h2, rowptr, edges, dinv, bias, node, l, acc0, acc1);
    *(float2*)(g + (size_t)node * 64 + 2 * l) = make_float2(acc0, acc1);
}

// layer 2 + fused final: out = relu(agg)@M + op@Wfc_bot + cvec
__global__ __launch_bounds__(256) void agg2f_k(const unsigned short* __restrict__ h2,
                                               const int* __restrict__ rowptr,
                                               const int2* __restrict__ edges,
                                               const float* __restrict__ dinv,
                                               const float* __restrict__ bias,
                                               const float* __restrict__ op,
                                               const float* __restrict__ M,
                                               const float* __restrict__ Wfc,
                                               const float* __restrict__ cvec,
                                               float* __restrict__ out, int N) {
    int wid = (blockIdx.x * 256 + threadIdx.x) >> 6;
    int lane = threadIdx.x & 63;
    int node = wid * 2 + (lane >> 5);
    int l = lane & 31;
    if (node >= N) return;
    float acc0, acc1;
    agg_core(h2, rowptr, edges, dinv, bias, node, l, acc0, acc1);
    float2 ov = *(const float2*)(op + (size_t)node * 64 + 2 * l);
    int f0 = 2 * l, f1 = 2 * l + 1;
    float p0 = acc0 * M[f0 * 2 + 0] + acc1 * M[f1 * 2 + 0]
             + ov.x * Wfc[(IN_C + f0) * 2 + 0] + ov.y * Wfc[(IN_C + f1) * 2 + 0];
    float p1 = acc0 * M[f0 * 2 + 1] + acc1 * M[f1 * 2 + 1]
             + ov.x * Wfc[(IN_C + f0) * 2 + 1] + ov.y * Wfc[(IN_C + f1) * 2 + 1];
    #pragma unroll
    for (int off = 16; off > 0; off >>= 1) {
        p0 += __shfl_xor(p0, off);
        p1 += __shfl_xor(p1, off);
    }
    if (l == 0)
        *(float2*)(out + (size_t)node * 2) = make_float2(p0 + cvec[0], p1 + cvec[1]);
}

// ---------------- fold Wp@Wfc_top and bp@Wfc_top+bfc ----------------
__global__ __launch_bounds__(256) void prem_k(const float* __restrict__ Wp,
                                              const float* __restrict__ bp,
                                              const float* __restrict__ Wfc,
                                              const float* __restrict__ bfc,
                                              float* M, float* cvec) {
    int t = threadIdx.x;
    if (t < 128) {
        int k = t >> 1, j = t & 1;
        float s = 0.f;
        for (int f = 0; f < IN_C; ++f) s += Wp[k * IN_C + f] * Wfc[f * 2 + j];
        M[t] = s;
    } else if (t < 130) {
        int j = t - 128;
        float s = bfc[j];
        for (int f = 0; f < IN_C; ++f) s += bp[f] * Wfc[f * 2 + j];
        cvec[j] = s;
    }
}

extern "C" void kernel_launch(void* const* d_in, const int* in_sizes, int n_in,
                              void* d_out, int out_size, void* d_ws, size_t ws_size,
                              hipStream_t stream) {
    const float* x    = (const float*)d_in[0];
    const int*   ei   = (const int*)d_in[1];
    const float* attr = (const float*)d_in[2];
    const float* op   = (const float*)d_in[3];
    const float* W1   = (const float*)d_in[4];
    const float* b1   = (const float*)d_in[5];
    const float* W2   = (const float*)d_in[6];
    const float* b2   = (const float*)d_in[7];
    const float* Wp   = (const float*)d_in[8];
    const float* bp   = (const float*)d_in[9];
    const float* Wfc  = (const float*)d_in[10];
    const float* bfc  = (const float*)d_in[11];

    const int N = in_sizes[0] / IN_C;
    const int E = in_sizes[2];
    const int* row = ei;
    const int* col = ei + E;

    const int B     = (N + NPB - 1) >> NPB_SHIFT;
    const int nblk1 = (E + EPB - 1) / EPB;

    char* base = (char*)d_ws;
    size_t off = 0;
    auto alloc = [&](size_t bytes) -> char* {
        char* p = base + off;
        off = (off + bytes + 255) & ~(size_t)255;
        return p;
    };
    int2*  edges  = (int2*)alloc((size_t)E * 8);          // persistent CSR
    // region A: bsw (E*8) -> later h2 bf16 (N*64*2)
    size_t h2_b   = (size_t)N * HID * 2;
    char*  regA   = alloc((size_t)E * 8 > h2_b ? (size_t)E * 8 : h2_b);
    int2*  bsw    = (int2*)regA;
    unsigned short* h2 = (unsigned short*)regA;
    // region B: bcol (E*4) + blk_off (nblk1*MAXB*4) -> later g fp32 (N*64*4)
    size_t bcol_b = (size_t)E * 4;
    size_t regB_b = ((bcol_b + 255) & ~(size_t)255) + (size_t)nblk1 * MAXB * 4;
    size_t g_b    = (size_t)N * HID * 4;
    char*  regB   = alloc(regB_b > g_b ? regB_b : g_b);
    int*   bcol   = (int*)regB;
    int*   blkoff = (int*)(regB + ((bcol_b + 255) & ~(size_t)255));
    float* g      = (float*)regB;
    float* dinv   = (float*)alloc((size_t)N * 4);
    int*   rowptr = (int*)alloc((size_t)(N + 1) * 4);
    int*   gcnt   = (int*)alloc((size_t)MAXB * 4);
    int*   bptr   = (int*)alloc((size_t)(MAXB + 1) * 4);
    float* Mbuf   = (float*)alloc(512);
    float* cvec   = (float*)alloc(64);

    const int gAgg = (((N + 1) / 2) * 64 + 255) / 256;

    zero_k<<<(B + 255) / 256, 256, 0, stream>>>(gcnt, B);
    prem_k<<<1, 256, 0, stream>>>(Wp, bp, Wfc, bfc, Mbuf, cvec);
    p1a_k<<<nblk1, BINB, 0, stream>>>(col, gcnt, blkoff, E, B);
    scanB_k<<<1, 256, 0, stream>>>(gcnt, bptr, B, E);
    p1b_k<<<nblk1, BINB, 0, stream>>>(row, col, attr, blkoff, bptr, bsw, bcol, E, B);
    p2_k<<<B, 256, 0, stream>>>(bsw, bcol, bptr, edges, rowptr, dinv, N, E);

    // conv1: h2 = bf16(x @ W1) ; g = relu(agg(h2) + b1)   (h2 overlays bsw)
    gemm_k<<<(N + 63) / 64, 256, 0, stream>>>(x, W1, h2, N, IN_C);
    agg1_k<<<gAgg, 256, 0, stream>>>(h2, g, rowptr, edges, dinv, b1, N);
    // conv2: h2 = bf16(g @ W2) ; out = relu(agg(h2)+b2)@M + op@Wfc_bot + cvec
    gemm_k<<<(N + 63) / 64, 256, 0, stream>>>(g, W2, h2, N, HID);
    agg2f_k<<<gAgg, 256, 0, stream>>>(h2, rowptr, edges, dinv, b2, op, Mbuf, Wfc, cvec,
                                      (float*)d_out, N);
}